// Round 1
// baseline (86.919 us; speedup 1.0000x reference)
//
#include <hip/hip_runtime.h>

// B=1, C=32, D=64, H=128, W=128. float32 in/out.
// Recurrence (reverse along D): for d = D-1 .. 0:
//   h = z[d]*_h[d] + (1-z[d])*h_prev;  out[d] = h;  h_prev = h;
// h_prev initialized from h0 (shape C,1,H,W).

#define GRU_C  32
#define GRU_D  64
#define GRU_HW (128 * 128)
#define VEC4_PER_PLANE (GRU_HW / 4)   // 4096 float4 per (c,d) plane

__global__ __launch_bounds__(256) void gru_rev_scan_kernel(
    const float4* __restrict__ z,
    const float4* __restrict__ h,
    const float4* __restrict__ h0,
    float4* __restrict__ out)
{
    const int tid = blockIdx.x * blockDim.x + threadIdx.x;  // 0 .. C*HW/4 - 1
    const int c = tid / VEC4_PER_PLANE;
    const int p = tid - c * VEC4_PER_PLANE;

    // base index (in float4 units) of (c, d=0) plane + pixel p
    const int base = c * (GRU_D * VEC4_PER_PLANE) + p;

    float4 hp = h0[c * VEC4_PER_PLANE + p];

    #pragma unroll 4
    for (int d = GRU_D - 1; d >= 0; --d) {
        const int idx = base + d * VEC4_PER_PLANE;
        const float4 zt = z[idx];
        const float4 ht = h[idx];
        float4 hn;
        hn.x = fmaf(zt.x, ht.x, (1.0f - zt.x) * hp.x);
        hn.y = fmaf(zt.y, ht.y, (1.0f - zt.y) * hp.y);
        hn.z = fmaf(zt.z, ht.z, (1.0f - zt.z) * hp.z);
        hn.w = fmaf(zt.w, ht.w, (1.0f - zt.w) * hp.w);
        out[idx] = hn;
        hp = hn;
    }
}

extern "C" void kernel_launch(void* const* d_in, const int* in_sizes, int n_in,
                              void* d_out, int out_size, void* d_ws, size_t ws_size,
                              hipStream_t stream) {
    const float4* z  = (const float4*)d_in[0];
    const float4* h  = (const float4*)d_in[1];
    const float4* h0 = (const float4*)d_in[2];
    float4* out = (float4*)d_out;

    const int total_threads = GRU_C * VEC4_PER_PLANE;  // 131072
    const int block = 256;
    const int grid = total_threads / block;            // 512

    gru_rev_scan_kernel<<<grid, block, 0, stream>>>(z, h, h0, out);
}

// Round 2
// 82.939 us; speedup vs baseline: 1.0480x; 1.0480x over previous
//
#include <hip/hip_runtime.h>

// B=1, C=32, D=64, H=128, W=128. float32 in/out.
// Reverse scan along D: for d = D-1 .. 0:
//   h = z[d]*_h[d] + (1-z[d])*h_prev;  out[d] = h;  h_prev = h;
// h_prev initialized from h0 (shape C,1,H,W).
//
// R2: float2 per lane (8 B) instead of float4 -> 2x threads (262144),
// 16 waves/CU, unroll 8 for MLP. Latency-bound fix, traffic unchanged.

#define GRU_C  32
#define GRU_D  64
#define GRU_HW (128 * 128)
#define VEC2_PER_PLANE (GRU_HW / 2)   // 8192 float2 per (c,d) plane

__global__ __launch_bounds__(256) void gru_rev_scan_kernel(
    const float2* __restrict__ z,
    const float2* __restrict__ h,
    const float2* __restrict__ h0,
    float2* __restrict__ out)
{
    const int tid = blockIdx.x * blockDim.x + threadIdx.x;  // 0 .. C*HW/2 - 1
    const int c = tid >> 13;          // / 8192
    const int p = tid & (VEC2_PER_PLANE - 1);

    const int base = c * (GRU_D * VEC2_PER_PLANE) + p;

    float2 hp = h0[c * VEC2_PER_PLANE + p];

    #pragma unroll 8
    for (int d = GRU_D - 1; d >= 0; --d) {
        const int idx = base + d * VEC2_PER_PLANE;
        const float2 zt = z[idx];
        const float2 ht = h[idx];
        float2 hn;
        hn.x = fmaf(zt.x, ht.x, (1.0f - zt.x) * hp.x);
        hn.y = fmaf(zt.y, ht.y, (1.0f - zt.y) * hp.y);
        out[idx] = hn;
        hp = hn;
    }
}

extern "C" void kernel_launch(void* const* d_in, const int* in_sizes, int n_in,
                              void* d_out, int out_size, void* d_ws, size_t ws_size,
                              hipStream_t stream) {
    const float2* z  = (const float2*)d_in[0];
    const float2* h  = (const float2*)d_in[1];
    const float2* h0 = (const float2*)d_in[2];
    float2* out = (float2*)d_out;

    const int total_threads = GRU_C * VEC2_PER_PLANE;  // 262144
    const int block = 256;
    const int grid = total_threads / block;            // 1024

    gru_rev_scan_kernel<<<grid, block, 0, stream>>>(z, h, h0, out);
}

// Round 3
// 79.272 us; speedup vs baseline: 1.0965x; 1.0463x over previous
//
#include <hip/hip_runtime.h>

// B=1, C=32, D=64, H=128, W=128. float32 in/out.
// Reverse scan along D: for d = D-1 .. 0:
//   h = z[d]*_h[d] + (1-z[d])*h_prev;  out[d] = h;  h_prev = h;
// h_prev initialized from h0 (shape C,1,H,W).
//
// R3: scalar float per lane -> 524288 threads = 8192 waves = 100% launch
// occupancy. Explicit 8-deep chunk prefetch into statically-indexed register
// arrays forces 16 outstanding loads/wave (R2's VGPR_Count=32 showed the
// compiler wasn't pipelining). ~48 VGPR, under the 64-VGPR occupancy cliff.

#define GRU_C  32
#define GRU_D  64
#define GRU_HW (128 * 128)
#define CHUNK  8

__global__ __launch_bounds__(256) void gru_rev_scan_kernel(
    const float* __restrict__ z,
    const float* __restrict__ h,
    const float* __restrict__ h0,
    float* __restrict__ out)
{
    const int tid = blockIdx.x * blockDim.x + threadIdx.x;  // 0 .. C*HW - 1
    const int c = tid >> 14;              // / 16384
    const int p = tid & (GRU_HW - 1);

    const int base = c * (GRU_D * GRU_HW) + p;

    float hp = h0[c * GRU_HW + p];

    // chunks of CHUNK d-values, walking d downward: d0 = 56, 48, ..., 0
    for (int d0 = GRU_D - CHUNK; d0 >= 0; d0 -= CHUNK) {
        float zb[CHUNK], hb[CHUNK], ob[CHUNK];

        // batch-issue all loads for this chunk (independent, known addresses)
        #pragma unroll
        for (int k = 0; k < CHUNK; ++k) {
            const int idx = base + (d0 + k) * GRU_HW;
            zb[k] = z[idx];
            hb[k] = h[idx];
        }

        // serial recurrence within the chunk (d descending => k descending)
        #pragma unroll
        for (int k = CHUNK - 1; k >= 0; --k) {
            hp = fmaf(zb[k], hb[k], (1.0f - zb[k]) * hp);
            ob[k] = hp;
        }

        // batch stores
        #pragma unroll
        for (int k = 0; k < CHUNK; ++k) {
            out[base + (d0 + k) * GRU_HW] = ob[k];
        }
    }
}

extern "C" void kernel_launch(void* const* d_in, const int* in_sizes, int n_in,
                              void* d_out, int out_size, void* d_ws, size_t ws_size,
                              hipStream_t stream) {
    const float* z  = (const float*)d_in[0];
    const float* h  = (const float*)d_in[1];
    const float* h0 = (const float*)d_in[2];
    float* out = (float*)d_out;

    const int total_threads = GRU_C * GRU_HW;  // 524288
    const int block = 256;
    const int grid = total_threads / block;    // 2048

    gru_rev_scan_kernel<<<grid, block, 0, stream>>>(z, h, h0, out);
}

// Round 4
// 62.469 us; speedup vs baseline: 1.3914x; 1.2690x over previous
//
#include <hip/hip_runtime.h>

// B=1, C=32, D=64, H=128, W=128. float32 in/out.
// Reverse scan along D: for d = D-1 .. 0:
//   h = z[d]*_h[d] + (1-z[d])*h_prev;  out[d] = h;  h_prev = h;
//
// R4: R3 structure + NON-TEMPORAL stores for out. Inputs (260 MB) nearly fit
// in the 256 MB Infinity Cache; the 128 MB output stream allocating in cache
// is what evicts them between replays (replay FETCH==132 MB == half the
// inputs). nt stores -> inputs stay L3-resident -> HBM traffic ~= writes only.

#define GRU_C  32
#define GRU_D  64
#define GRU_HW (128 * 128)
#define CHUNK  8

__global__ __launch_bounds__(256) void gru_rev_scan_kernel(
    const float* __restrict__ z,
    const float* __restrict__ h,
    const float* __restrict__ h0,
    float* __restrict__ out)
{
    const int tid = blockIdx.x * blockDim.x + threadIdx.x;  // 0 .. C*HW - 1
    const int c = tid >> 14;              // / 16384
    const int p = tid & (GRU_HW - 1);

    const int base = c * (GRU_D * GRU_HW) + p;

    float hp = h0[c * GRU_HW + p];

    for (int d0 = GRU_D - CHUNK; d0 >= 0; d0 -= CHUNK) {
        float zb[CHUNK], hb[CHUNK], ob[CHUNK];

        #pragma unroll
        for (int k = 0; k < CHUNK; ++k) {
            const int idx = base + (d0 + k) * GRU_HW;
            zb[k] = z[idx];
            hb[k] = h[idx];
        }

        #pragma unroll
        for (int k = CHUNK - 1; k >= 0; --k) {
            hp = fmaf(zb[k], hb[k], (1.0f - zb[k]) * hp);
            ob[k] = hp;
        }

        #pragma unroll
        for (int k = 0; k < CHUNK; ++k) {
            __builtin_nontemporal_store(ob[k], &out[base + (d0 + k) * GRU_HW]);
        }
    }
}

extern "C" void kernel_launch(void* const* d_in, const int* in_sizes, int n_in,
                              void* d_out, int out_size, void* d_ws, size_t ws_size,
                              hipStream_t stream) {
    const float* z  = (const float*)d_in[0];
    const float* h  = (const float*)d_in[1];
    const float* h0 = (const float*)d_in[2];
    float* out = (float*)d_out;

    const int total_threads = GRU_C * GRU_HW;  // 524288
    const int block = 256;
    const int grid = total_threads / block;    // 2048

    gru_rev_scan_kernel<<<grid, block, 0, stream>>>(z, h, h0, out);
}